// Round 1
// baseline (3080.777 us; speedup 1.0000x reference)
//
#include <hip/hip_runtime.h>

#define N_NODES 50000
#define N_EDGES 800000
#define NODE_IN 256
#define EDGE_IN 64
#define HID 128
#define OUTD 16
#define LN_EPS 1e-5f

typedef __attribute__((ext_vector_type(4))) float f32x4;
typedef __attribute__((ext_vector_type(8))) _Float16 half8;
typedef __attribute__((ext_vector_type(4))) _Float16 half4;

__device__ __forceinline__ float gelu_exact(float x) {
    return 0.5f * x * (1.0f + erff(x * 0.70710678118654752f));
}

// ---------------------------------------------------------------------------
// Setup: transpose weights to [col][k] fp16 so MFMA B-fragments (8 k-contig
// halves per lane) are 16B vector loads.
// ---------------------------------------------------------------------------
__global__ void setup_kernel(const float* __restrict__ Wn, const float* __restrict__ We,
                             _Float16* __restrict__ WTn, _Float16* __restrict__ WTe) {
    int t = blockIdx.x * blockDim.x + threadIdx.x;
    int stride = gridDim.x * blockDim.x;
    for (int i = t; i < HID * NODE_IN; i += stride) {
        int n = i >> 8, k = i & 255;
        WTn[i] = (_Float16)Wn[k * HID + n];
    }
    for (int i = t; i < HID * EDGE_IN; i += stride) {
        int n = i >> 6, k = i & 63;
        WTe[i] = (_Float16)We[k * HID + n];
    }
}

// ---------------------------------------------------------------------------
// Node projection: hv = LN(GELU(X @ Wn)), stored fp16 in PERMUTED layout:
// hv[row*128 + x*8 + c] = value at col (16c + x).  Block = 256 thr = 4 waves,
// tile = 64 rows x 128 cols, K-loop in chunks of 64.  LDS rows padded to 72
// halves (144B, 16B-aligned) to spread ds_read_b128 banks.
// ---------------------------------------------------------------------------
__global__ __launch_bounds__(256) void node_kernel(
    const float* __restrict__ X,
    const _Float16* __restrict__ WT,    // [HID][NODE_IN]
    const float* __restrict__ g, const float* __restrict__ b,
    _Float16* __restrict__ hv)
{
    __shared__ __align__(16) _Float16 lA[64 * 72];
    __shared__ __align__(16) _Float16 lB[128 * 72];

    const int t = threadIdx.x;
    const int wave = t >> 6, lane = t & 63;
    const int x15 = lane & 15, quad = lane >> 4;
    const int row0 = blockIdx.x * 64;

    float gc[8], bc[8];
    #pragma unroll
    for (int c = 0; c < 8; ++c) { gc[c] = g[16 * c + x15]; bc[c] = b[16 * c + x15]; }

    f32x4 acc[8];
    #pragma unroll
    for (int c = 0; c < 8; ++c) acc[c] = (f32x4)(0.0f);

    for (int kc = 0; kc < 4; ++kc) {
        const int k0 = kc * 64;
        __syncthreads();
        // stage A: 64 rows x 64 k, fp32 -> fp16 (coalesced: 16 lanes = 256B/row-seg)
        #pragma unroll
        for (int j = 0; j < 4; ++j) {
            int idx = j * 1024 + t * 4;        // float index within tile
            int r = idx >> 6, kk = idx & 63;
            int grow = row0 + r;
            float4 v = make_float4(0.f, 0.f, 0.f, 0.f);
            if (grow < N_NODES) v = *(const float4*)(X + grow * NODE_IN + k0 + kk);
            half4 h4;
            h4[0] = (_Float16)v.x; h4[1] = (_Float16)v.y;
            h4[2] = (_Float16)v.z; h4[3] = (_Float16)v.w;
            *(half4*)(lA + r * 72 + kk) = h4;
        }
        // stage B: WT[:, k0..k0+63] (128 x 64 halves)
        #pragma unroll
        for (int j = 0; j < 4; ++j) {
            int idx = j * 2048 + t * 8;        // half index within tile
            int n = idx >> 6, kk = idx & 63;
            half8 v = *(const half8*)(WT + n * NODE_IN + k0 + kk);
            *(half8*)(lB + n * 72 + kk) = v;
        }
        __syncthreads();
        #pragma unroll
        for (int ks = 0; ks < 2; ++ks) {
            half8 a = *(const half8*)(lA + (wave * 16 + x15) * 72 + ks * 32 + quad * 8);
            #pragma unroll
            for (int c = 0; c < 8; ++c) {
                half8 bb = *(const half8*)(lB + (c * 16 + x15) * 72 + ks * 32 + quad * 8);
                acc[c] = __builtin_amdgcn_mfma_f32_16x16x32_f16(a, bb, acc[c], 0, 0, 0);
            }
        }
    }

    // epilogue: GELU -> row LN (16-lane shfl reduce) -> permuted fp16 store
    float v[8][4], s[4], sq[4];
    #pragma unroll
    for (int r = 0; r < 4; ++r) { s[r] = 0.f; sq[r] = 0.f; }
    #pragma unroll
    for (int c = 0; c < 8; ++c)
        #pragma unroll
        for (int r = 0; r < 4; ++r) {
            float x = gelu_exact(acc[c][r]);
            v[c][r] = x; s[r] += x; sq[r] += x * x;
        }
    #pragma unroll
    for (int m = 1; m <= 8; m <<= 1)
        #pragma unroll
        for (int r = 0; r < 4; ++r) {
            s[r]  += __shfl_xor(s[r],  m, 64);
            sq[r] += __shfl_xor(sq[r], m, 64);
        }
    #pragma unroll
    for (int r = 0; r < 4; ++r) {
        int row = row0 + wave * 16 + quad * 4 + r;   // D row = quad*4 + reg
        if (row >= N_NODES) continue;
        float mean = s[r] * (1.f / 128.f);
        float var  = sq[r] * (1.f / 128.f) - mean * mean;
        float rstd = rsqrtf(var + LN_EPS);
        half8 o;
        #pragma unroll
        for (int c = 0; c < 8; ++c)
            o[c] = (_Float16)((v[c][r] - mean) * rstd * gc[c] + bc[c]);
        *(half8*)(hv + row * HID + x15 * 8) = o;
    }
}

// ---------------------------------------------------------------------------
// Fused edge kernel: per 64-edge batch, MFMA edge-proj (K=64, W resident in
// 64 VGPRs) -> LN -> exp -> gather hv[src] (16B half8, permuted layout) ->
// fp32 atomicAdd into h[dst] (permuted layout, 8 consecutive floats/lane).
// he is never materialized.
// ---------------------------------------------------------------------------
__global__ __launch_bounds__(256) void edge_kernel(
    const float* __restrict__ EF,
    const int* __restrict__ src, const int* __restrict__ dst,
    const _Float16* __restrict__ WT,    // [HID][EDGE_IN]
    const float* __restrict__ g, const float* __restrict__ b,
    const _Float16* __restrict__ hv,
    float* __restrict__ h)
{
    __shared__ __align__(16) _Float16 lA[64 * 72];
    __shared__ int lsrc[64];
    __shared__ int ldst[64];

    const int t = threadIdx.x;
    const int wave = t >> 6, lane = t & 63;
    const int x15 = lane & 15, quad = lane >> 4;

    // B fragments resident in registers (W constant over all edges): 64 VGPRs
    half8 Bf[8][2];
    #pragma unroll
    for (int c = 0; c < 8; ++c)
        #pragma unroll
        for (int ks = 0; ks < 2; ++ks)
            Bf[c][ks] = *(const half8*)(WT + (c * 16 + x15) * EDGE_IN + ks * 32 + quad * 8);

    float gc[8], bc[8];
    #pragma unroll
    for (int c = 0; c < 8; ++c) { gc[c] = g[16 * c + x15]; bc[c] = b[16 * c + x15]; }

    const int nbatch = N_EDGES / 64;   // 12500 exact
    for (int batch = blockIdx.x; batch < nbatch; batch += gridDim.x) {
        const int e0 = batch * 64;
        __syncthreads();   // protect lA/lsrc/ldst reuse
        // stage A: 64 edges x 64 feats fp32 -> fp16, fully coalesced (wave = 1KB contig)
        #pragma unroll
        for (int j = 0; j < 4; ++j) {
            int idx = j * 1024 + t * 4;
            int r = idx >> 6, kk = idx & 63;
            float4 v = *(const float4*)(EF + (e0 + r) * EDGE_IN + kk);
            half4 h4;
            h4[0] = (_Float16)v.x; h4[1] = (_Float16)v.y;
            h4[2] = (_Float16)v.z; h4[3] = (_Float16)v.w;
            *(half4*)(lA + r * 72 + kk) = h4;
        }
        if (t < 64) lsrc[t] = src[e0 + t];
        else if (t < 128) ldst[t - 64] = dst[e0 + t - 64];
        __syncthreads();

        f32x4 acc[8];
        #pragma unroll
        for (int c = 0; c < 8; ++c) acc[c] = (f32x4)(0.0f);
        #pragma unroll
        for (int ks = 0; ks < 2; ++ks) {
            half8 a = *(const half8*)(lA + (wave * 16 + x15) * 72 + ks * 32 + quad * 8);
            #pragma unroll
            for (int c = 0; c < 8; ++c)
                acc[c] = __builtin_amdgcn_mfma_f32_16x16x32_f16(a, Bf[c][ks], acc[c], 0, 0, 0);
        }

        // LN stats per edge-row
        float s[4], sq[4];
        #pragma unroll
        for (int r = 0; r < 4; ++r) { s[r] = 0.f; sq[r] = 0.f; }
        #pragma unroll
        for (int c = 0; c < 8; ++c)
            #pragma unroll
            for (int r = 0; r < 4; ++r) { float x = acc[c][r]; s[r] += x; sq[r] += x * x; }
        #pragma unroll
        for (int m = 1; m <= 8; m <<= 1)
            #pragma unroll
            for (int r = 0; r < 4; ++r) {
                s[r]  += __shfl_xor(s[r],  m, 64);
                sq[r] += __shfl_xor(sq[r], m, 64);
            }

        #pragma unroll
        for (int r = 0; r < 4; ++r) {
            int erow = wave * 16 + quad * 4 + r;
            int se = lsrc[erow], de = ldst[erow];
            float mean = s[r] * (1.f / 128.f);
            float var  = sq[r] * (1.f / 128.f) - mean * mean;
            float rstd = rsqrtf(var + LN_EPS);
            half8 hg = *(const half8*)(hv + se * HID + x15 * 8);
            float* hb = h + de * HID + x15 * 8;
            #pragma unroll
            for (int c = 0; c < 8; ++c) {
                float he = __expf((acc[c][r] - mean) * rstd * gc[c] + bc[c]);
                atomicAdd(hb + c, he * (float)hg[c]);
            }
        }
    }
}

// ---------------------------------------------------------------------------
// Out projection: out = LN(GELU(h @ Wout)).  h is in permuted layout; the LDS
// staging un-permutes.  16 nodes/block, 16 lanes per node.
// ---------------------------------------------------------------------------
__global__ __launch_bounds__(256) void out_kernel(
    const float* __restrict__ h,
    const float* __restrict__ W,       // [128][16]
    const float* __restrict__ g, const float* __restrict__ b,
    float* __restrict__ out)
{
    __shared__ float lW[HID * OUTD];
    __shared__ float lh[16][HID];
    const int t = threadIdx.x;
    const int node0 = blockIdx.x * 16;

    for (int i = t; i < HID * OUTD; i += 256) lW[i] = W[i];
    for (int i = t; i < 16 * HID; i += 256) {
        int row = i >> 7, p = i & 127;
        int k = 16 * (p & 7) + (p >> 3);     // un-permute: p = x*8 + c -> k = 16c + x
        int grow = node0 + row;
        lh[row][k] = (grow < N_NODES) ? h[grow * HID + p] : 0.f;
    }
    __syncthreads();

    const int i = t >> 4, j = t & 15;
    float acc = 0.f;
    #pragma unroll 8
    for (int k = 0; k < HID; ++k)
        acc = fmaf(lh[i][k], lW[k * OUTD + j], acc);
    float x = gelu_exact(acc);
    float s = x, sq = x * x;
    #pragma unroll
    for (int m = 1; m <= 8; m <<= 1) {
        s  += __shfl_xor(s,  m, 64);
        sq += __shfl_xor(sq, m, 64);
    }
    float mean = s * (1.f / 16.f);
    float var  = sq * (1.f / 16.f) - mean * mean;
    float rstd = rsqrtf(var + LN_EPS);
    int grow = node0 + i;
    if (grow < N_NODES) out[grow * OUTD + j] = (x - mean) * rstd * g[j] + b[j];
}

// ---------------------------------------------------------------------------
extern "C" void kernel_launch(void* const* d_in, const int* in_sizes, int n_in,
                              void* d_out, int out_size, void* d_ws, size_t ws_size,
                              hipStream_t stream) {
    const float* node_feats = (const float*)d_in[0];
    const float* edge_feats = (const float*)d_in[1];
    const int*   src        = (const int*)d_in[2];
    const int*   dst        = (const int*)d_in[3];
    const float* W_node     = (const float*)d_in[4];
    const float* g_node     = (const float*)d_in[5];
    const float* b_node     = (const float*)d_in[6];
    const float* W_edge     = (const float*)d_in[7];
    const float* g_edge     = (const float*)d_in[8];
    const float* b_edge     = (const float*)d_in[9];
    const float* W_out      = (const float*)d_in[10];
    const float* g_out      = (const float*)d_in[11];
    const float* b_out      = (const float*)d_in[12];
    float* out = (float*)d_out;

    char* ws = (char*)d_ws;
    _Float16* hv  = (_Float16*)(ws);                           // 50000*128*2 = 12,800,000 B
    float*    h   = (float*)(ws + 12800000);                   // 50000*128*4 = 25,600,000 B
    _Float16* WTn = (_Float16*)(ws + 12800000 + 25600000);     // 128*256*2   =      65,536 B
    _Float16* WTe = WTn + HID * NODE_IN;                       // 128*64*2    =      16,384 B

    hipMemsetAsync(h, 0, (size_t)N_NODES * HID * sizeof(float), stream);
    setup_kernel<<<64, 256, 0, stream>>>(W_node, W_edge, WTn, WTe);
    node_kernel<<<(N_NODES + 63) / 64, 256, 0, stream>>>(node_feats, WTn, g_node, b_node, hv);
    edge_kernel<<<1250, 256, 0, stream>>>(edge_feats, src, dst, WTe, g_edge, b_edge, hv, h);
    out_kernel<<<(N_NODES + 15) / 16, 256, 0, stream>>>(h, W_out, g_out, b_out, out);
}

// Round 3
// 1434.867 us; speedup vs baseline: 2.1471x; 2.1471x over previous
//
#include <hip/hip_runtime.h>

#define N_NODES 50000
#define N_EDGES 800000
#define NODE_IN 256
#define EDGE_IN 64
#define HID 128
#define OUTD 16
#define LN_EPS 1e-5f
#define NCHUNK 64
#define EPC (N_EDGES / NCHUNK)   // 12500 edges per chunk

typedef __attribute__((ext_vector_type(4))) float f32x4;
typedef __attribute__((ext_vector_type(8))) _Float16 half8;
typedef __attribute__((ext_vector_type(4))) _Float16 half4;

__device__ __forceinline__ float gelu_exact(float x) {
    return 0.5f * x * (1.0f + erff(x * 0.70710678118654752f));
}

// ---------------------------------------------------------------------------
// Setup: transpose weights to [col][k] fp16 (MFMA B fragments become 16B loads)
// ---------------------------------------------------------------------------
__global__ void setup_kernel(const float* __restrict__ Wn, const float* __restrict__ We,
                             _Float16* __restrict__ WTn, _Float16* __restrict__ WTe) {
    int t = blockIdx.x * blockDim.x + threadIdx.x;
    int stride = gridDim.x * blockDim.x;
    for (int i = t; i < HID * NODE_IN; i += stride) {
        int n = i >> 8, k = i & 255;
        WTn[i] = (_Float16)Wn[k * HID + n];
    }
    for (int i = t; i < HID * EDGE_IN; i += stride) {
        int n = i >> 6, k = i & 63;
        WTe[i] = (_Float16)We[k * HID + n];
    }
}

// ---------------------------------------------------------------------------
// Deterministic stable counting sort by dst.
// Pass A: per-chunk histograms (integer atomics -> deterministic counts).
// ---------------------------------------------------------------------------
__global__ __launch_bounds__(256) void hist_kernel(const int* __restrict__ dst,
                                                   int* __restrict__ hist) {
    const int k = blockIdx.x;
    int* hk = hist + k * N_NODES;
    const int beg = k * EPC;
    for (int i = threadIdx.x; i < EPC; i += 256)
        atomicAdd(&hk[dst[beg + i]], 1);
}

// Pass B1: per-node totals across chunks.
__global__ __launch_bounds__(256) void tot_kernel(const int* __restrict__ hist,
                                                  int* __restrict__ tot) {
    int n = blockIdx.x * 256 + threadIdx.x;
    if (n < N_NODES) {
        int s = 0;
        for (int k = 0; k < NCHUNK; ++k) s += hist[k * N_NODES + n];
        tot[n] = s;
    }
}

// Scan over tot -> offs (exclusive).  49 blocks x 1024 elements.
__global__ __launch_bounds__(256) void scan1_kernel(const int* __restrict__ tot,
                                                    int* __restrict__ offs,
                                                    int* __restrict__ btot) {
    __shared__ int lsum[256];
    const int t = threadIdx.x;
    const int base = blockIdx.x * 1024 + t * 4;
    int v[4]; int s = 0;
    #pragma unroll
    for (int j = 0; j < 4; ++j) {
        int idx = base + j;
        v[j] = (idx < N_NODES) ? tot[idx] : 0;
        s += v[j];
    }
    lsum[t] = s;
    __syncthreads();
    for (int d = 1; d < 256; d <<= 1) {
        int x = (t >= d) ? lsum[t - d] : 0;
        __syncthreads();
        lsum[t] += x;
        __syncthreads();
    }
    int excl = lsum[t] - s;
    if (t == 255) btot[blockIdx.x] = lsum[255];
    int run = excl;
    #pragma unroll
    for (int j = 0; j < 4; ++j) {
        int idx = base + j;
        if (idx < N_NODES) offs[idx] = run;
        run += v[j];
    }
}

__global__ __launch_bounds__(256) void scan2_kernel(int* __restrict__ offs,
                                                    const int* __restrict__ btot) {
    int s = 0;
    for (int i = 0; i < (int)blockIdx.x; ++i) s += btot[i];
    const int t = threadIdx.x;
    const int base = blockIdx.x * 1024 + t * 4;
    #pragma unroll
    for (int j = 0; j < 4; ++j) {
        int idx = base + j;
        if (idx < N_NODES) offs[idx] += s;
    }
    if (blockIdx.x == 0 && t == 0) offs[N_NODES] = N_EDGES;
}

// Pass B2: convert hist rows to per-chunk starting cursors (in place).
__global__ __launch_bounds__(256) void cursor_kernel(const int* __restrict__ offs,
                                                     int* __restrict__ hist) {
    int n = blockIdx.x * 256 + threadIdx.x;
    if (n < N_NODES) {
        int running = offs[n];
        for (int k = 0; k < NCHUNK; ++k) {
            int c = hist[k * N_NODES + n];
            hist[k * N_NODES + n] = running;
            running += c;
        }
    }
}

// Pass C: stable placement.  One block per chunk; 256-edge groups processed
// in order.  Rank within group via LDS-broadcast loop (deterministic); one
// leader per distinct dst per group advances the cursor with a single atomic
// (barrier-ordered across groups -> returned base is deterministic).
__global__ __launch_bounds__(256) void place_kernel(const int* __restrict__ src,
                                                    const int* __restrict__ dst,
                                                    int* __restrict__ cur,
                                                    int* __restrict__ perm,
                                                    int* __restrict__ psrc) {
    __shared__ int ld[256];
    __shared__ int ls[256];
    __shared__ int lb[256];
    const int k = blockIdx.x;
    const int t = threadIdx.x;
    int* curk = cur + k * N_NODES;
    const int cbeg = k * EPC;
    const int ngroups = (EPC + 255) / 256;   // 49, uniform across blocks
    for (int g = 0; g < ngroups; ++g) {
        const int gbeg = cbeg + g * 256;
        const int count = min(256, cbeg + EPC - gbeg);
        __syncthreads();                      // protect LDS reuse
        if (t < count) { ld[t] = dst[gbeg + t]; ls[t] = src[gbeg + t]; }
        __syncthreads();
        int rank = 0, leader = -1, total = 0;
        const int d = (t < count) ? ld[t] : -1;
        if (t < count) {
            #pragma unroll 4
            for (int i = 0; i < count; ++i) {
                bool m = (ld[i] == d);
                total += m;
                rank += (m && i < t);
                if (m && leader < 0) leader = i;
            }
            if (rank == 0) {                  // leader for this dst in this group
                int b = atomicAdd(&curk[d], total);
                lb[t] = b;
            }
        }
        __syncthreads();
        if (t < count) {
            int pos = lb[leader] + rank;
            perm[pos] = gbeg + t;
            psrc[pos] = ls[t];
        }
    }
}

// ---------------------------------------------------------------------------
// Node projection: hv = LN(GELU(X @ Wn)), stored fp16 PERMUTED:
// hv[row*128 + x*8 + c] = value at col (16c + x).
// ---------------------------------------------------------------------------
__global__ __launch_bounds__(256) void node_kernel(
    const float* __restrict__ X,
    const _Float16* __restrict__ WT,    // [HID][NODE_IN]
    const float* __restrict__ g, const float* __restrict__ b,
    _Float16* __restrict__ hv)
{
    __shared__ __align__(16) _Float16 lA[64 * 72];
    __shared__ __align__(16) _Float16 lB[128 * 72];

    const int t = threadIdx.x;
    const int wave = t >> 6, lane = t & 63;
    const int x15 = lane & 15, quad = lane >> 4;
    const int row0 = blockIdx.x * 64;

    float gc[8], bc[8];
    #pragma unroll
    for (int c = 0; c < 8; ++c) { gc[c] = g[16 * c + x15]; bc[c] = b[16 * c + x15]; }

    f32x4 acc[8];
    #pragma unroll
    for (int c = 0; c < 8; ++c) acc[c] = (f32x4)(0.0f);

    for (int kc = 0; kc < 4; ++kc) {
        const int k0 = kc * 64;
        __syncthreads();
        #pragma unroll
        for (int j = 0; j < 4; ++j) {
            int idx = j * 1024 + t * 4;
            int r = idx >> 6, kk = idx & 63;
            int grow = row0 + r;
            float4 v = make_float4(0.f, 0.f, 0.f, 0.f);
            if (grow < N_NODES) v = *(const float4*)(X + grow * NODE_IN + k0 + kk);
            half4 h4;
            h4[0] = (_Float16)v.x; h4[1] = (_Float16)v.y;
            h4[2] = (_Float16)v.z; h4[3] = (_Float16)v.w;
            *(half4*)(lA + r * 72 + kk) = h4;
        }
        #pragma unroll
        for (int j = 0; j < 4; ++j) {
            int idx = j * 2048 + t * 8;
            int n = idx >> 6, kk = idx & 63;
            half8 v = *(const half8*)(WT + n * NODE_IN + k0 + kk);
            *(half8*)(lB + n * 72 + kk) = v;
        }
        __syncthreads();
        #pragma unroll
        for (int ks = 0; ks < 2; ++ks) {
            half8 a = *(const half8*)(lA + (wave * 16 + x15) * 72 + ks * 32 + quad * 8);
            #pragma unroll
            for (int c = 0; c < 8; ++c) {
                half8 bb = *(const half8*)(lB + (c * 16 + x15) * 72 + ks * 32 + quad * 8);
                acc[c] = __builtin_amdgcn_mfma_f32_16x16x32_f16(a, bb, acc[c], 0, 0, 0);
            }
        }
    }

    float v[8][4], s[4], sq[4];
    #pragma unroll
    for (int r = 0; r < 4; ++r) { s[r] = 0.f; sq[r] = 0.f; }
    #pragma unroll
    for (int c = 0; c < 8; ++c)
        #pragma unroll
        for (int r = 0; r < 4; ++r) {
            float x = gelu_exact(acc[c][r]);
            v[c][r] = x; s[r] += x; sq[r] += x * x;
        }
    #pragma unroll
    for (int m = 1; m <= 8; m <<= 1)
        #pragma unroll
        for (int r = 0; r < 4; ++r) {
            s[r]  += __shfl_xor(s[r],  m, 64);
            sq[r] += __shfl_xor(sq[r], m, 64);
        }
    #pragma unroll
    for (int r = 0; r < 4; ++r) {
        int row = row0 + wave * 16 + quad * 4 + r;
        if (row >= N_NODES) continue;
        float mean = s[r] * (1.f / 128.f);
        float var  = sq[r] * (1.f / 128.f) - mean * mean;
        float rstd = rsqrtf(var + LN_EPS);
        half8 o;
        #pragma unroll
        for (int c = 0; c < 8; ++c)
            o[c] = (_Float16)((v[c][r] - mean) * rstd * gc[c] + bc[c]);
        *(half8*)(hv + row * HID + x15 * 8) = o;
    }
}

// ---------------------------------------------------------------------------
// Aggregation: one wave per dst node.  Edges sorted by dst (perm/psrc CSR,
// deterministic intra-bucket order).  Per 16-edge batch: A frags direct from
// global, MFMA with register-resident W_edge^T, LN -> exp -> gather hv[src]
// -> accumulate in registers.  One coalesced 512B store per node, zero atomics.
// ---------------------------------------------------------------------------
__global__ __launch_bounds__(256) void agg_kernel(
    const float* __restrict__ EF,
    const int* __restrict__ perm, const int* __restrict__ psrc,
    const int* __restrict__ offs,
    const _Float16* __restrict__ WT,    // [HID][EDGE_IN]
    const float* __restrict__ g, const float* __restrict__ b,
    const _Float16* __restrict__ hv,
    float* __restrict__ h)
{
    const int t = threadIdx.x;
    const int wave = t >> 6, lane = t & 63;
    const int x15 = lane & 15, quad = lane >> 4;
    const int n = blockIdx.x * 4 + wave;   // 12500 * 4 = 50000 exact

    half8 Bf[8][2];
    #pragma unroll
    for (int c = 0; c < 8; ++c)
        #pragma unroll
        for (int ks = 0; ks < 2; ++ks)
            Bf[c][ks] = *(const half8*)(WT + (c * 16 + x15) * EDGE_IN + ks * 32 + quad * 8);

    float gc[8], bc[8];
    #pragma unroll
    for (int c = 0; c < 8; ++c) { gc[c] = g[16 * c + x15]; bc[c] = b[16 * c + x15]; }

    const int beg = offs[n], end = offs[n + 1];

    f32x4 vacc[8];
    #pragma unroll
    for (int c = 0; c < 8; ++c) vacc[c] = (f32x4)(0.0f);

    for (int e0 = beg; e0 < end; e0 += 16) {
        int ea = e0 + x15;
        if (ea >= end) ea = end - 1;          // clamp: duplicate row, output masked
        int pe = perm[ea];
        const float* ep = EF + (size_t)pe * EDGE_IN;

        f32x4 acc[8];
        #pragma unroll
        for (int c = 0; c < 8; ++c) acc[c] = (f32x4)(0.0f);

        #pragma unroll
        for (int ks = 0; ks < 2; ++ks) {
            float4 f0 = *(const float4*)(ep + ks * 32 + quad * 8);
            float4 f1 = *(const float4*)(ep + ks * 32 + quad * 8 + 4);
            half8 a;
            a[0] = (_Float16)f0.x; a[1] = (_Float16)f0.y;
            a[2] = (_Float16)f0.z; a[3] = (_Float16)f0.w;
            a[4] = (_Float16)f1.x; a[5] = (_Float16)f1.y;
            a[6] = (_Float16)f1.z; a[7] = (_Float16)f1.w;
            #pragma unroll
            for (int c = 0; c < 8; ++c)
                acc[c] = __builtin_amdgcn_mfma_f32_16x16x32_f16(a, Bf[c][ks], acc[c], 0, 0, 0);
        }

        float s[4], sq[4];
        #pragma unroll
        for (int r = 0; r < 4; ++r) { s[r] = 0.f; sq[r] = 0.f; }
        #pragma unroll
        for (int c = 0; c < 8; ++c)
            #pragma unroll
            for (int r = 0; r < 4; ++r) { float x = acc[c][r]; s[r] += x; sq[r] += x * x; }
        #pragma unroll
        for (int m = 1; m <= 8; m <<= 1)
            #pragma unroll
            for (int r = 0; r < 4; ++r) {
                s[r]  += __shfl_xor(s[r],  m, 64);
                sq[r] += __shfl_xor(sq[r], m, 64);
            }

        #pragma unroll
        for (int r = 0; r < 4; ++r) {
            int er = e0 + quad * 4 + r;
            if (er < end) {
                int se = psrc[er];
                half8 hg = *(const half8*)(hv + (size_t)se * HID + x15 * 8);
                float mean = s[r] * (1.f / 128.f);
                float var  = sq[r] * (1.f / 128.f) - mean * mean;
                float rstd = rsqrtf(var + LN_EPS);
                #pragma unroll
                for (int c = 0; c < 8; ++c) {
                    float he = __expf((acc[c][r] - mean) * rstd * gc[c] + bc[c]);
                    vacc[c][r] += he * (float)hg[c];
                }
            }
        }
    }

    float o8[8];
    #pragma unroll
    for (int c = 0; c < 8; ++c) {
        float v = vacc[c][0] + vacc[c][1] + vacc[c][2] + vacc[c][3];
        v += __shfl_xor(v, 16, 64);
        v += __shfl_xor(v, 32, 64);
        o8[c] = v;
    }
    if (quad == 0) {
        float* hp = h + (size_t)n * HID + x15 * 8;   // permuted layout p = x15*8 + c
        float4 w0 = make_float4(o8[0], o8[1], o8[2], o8[3]);
        float4 w1 = make_float4(o8[4], o8[5], o8[6], o8[7]);
        *(float4*)hp = w0;
        *(float4*)(hp + 4) = w1;
    }
}

// ---------------------------------------------------------------------------
// Out projection: out = LN(GELU(h @ Wout)).  Un-permutes h in LDS staging.
// ---------------------------------------------------------------------------
__global__ __launch_bounds__(256) void out_kernel(
    const float* __restrict__ h,
    const float* __restrict__ W,       // [128][16]
    const float* __restrict__ g, const float* __restrict__ b,
    float* __restrict__ out)
{
    __shared__ float lW[HID * OUTD];
    __shared__ float lh[16][HID];
    const int t = threadIdx.x;
    const int node0 = blockIdx.x * 16;

    for (int i = t; i < HID * OUTD; i += 256) lW[i] = W[i];
    for (int i = t; i < 16 * HID; i += 256) {
        int row = i >> 7, p = i & 127;
        int k = 16 * (p & 7) + (p >> 3);     // un-permute: p = x*8 + c -> k = 16c + x
        int grow = node0 + row;
        lh[row][k] = (grow < N_NODES) ? h[grow * HID + p] : 0.f;
    }
    __syncthreads();

    const int i = t >> 4, j = t & 15;
    float acc = 0.f;
    #pragma unroll 8
    for (int k = 0; k < HID; ++k)
        acc = fmaf(lh[i][k], lW[k * OUTD + j], acc);
    float x = gelu_exact(acc);
    float s = x, sq = x * x;
    #pragma unroll
    for (int m = 1; m <= 8; m <<= 1) {
        s  += __shfl_xor(s,  m, 64);
        sq += __shfl_xor(sq, m, 64);
    }
    float mean = s * (1.f / 16.f);
    float var  = sq * (1.f / 16.f) - mean * mean;
    float rstd = rsqrtf(var + LN_EPS);
    int grow = node0 + i;
    if (grow < N_NODES) out[grow * OUTD + j] = (x - mean) * rstd * g[j] + b[j];
}

// ---------------------------------------------------------------------------
extern "C" void kernel_launch(void* const* d_in, const int* in_sizes, int n_in,
                              void* d_out, int out_size, void* d_ws, size_t ws_size,
                              hipStream_t stream) {
    const float* node_feats = (const float*)d_in[0];
    const float* edge_feats = (const float*)d_in[1];
    const int*   src        = (const int*)d_in[2];
    const int*   dst        = (const int*)d_in[3];
    const float* W_node     = (const float*)d_in[4];
    const float* g_node     = (const float*)d_in[5];
    const float* b_node     = (const float*)d_in[6];
    const float* W_edge     = (const float*)d_in[7];
    const float* g_edge     = (const float*)d_in[8];
    const float* b_edge     = (const float*)d_in[9];
    const float* W_out      = (const float*)d_in[10];
    const float* g_out      = (const float*)d_in[11];
    const float* b_out      = (const float*)d_in[12];
    float* out = (float*)d_out;

    char* ws = (char*)d_ws;
    size_t o = 0;
    _Float16* hv  = (_Float16*)(ws + o); o += (size_t)N_NODES * HID * 2;        // 12.8 MB
    float*    h   = (float*)(ws + o);    o += (size_t)N_NODES * HID * 4;        // 25.6 MB
    _Float16* WTn = (_Float16*)(ws + o); o += (size_t)HID * NODE_IN * 2;        // 64 KB
    _Float16* WTe = (_Float16*)(ws + o); o += (size_t)HID * EDGE_IN * 2;        // 16 KB
    int* tot  = (int*)(ws + o); o += (size_t)N_NODES * 4;                       // 200 KB
    int* offs = (int*)(ws + o); o += (size_t)(N_NODES + 16) * 4;                // 200 KB
    int* btot = (int*)(ws + o); o += 256;
    int* hist = (int*)(ws + o); o += (size_t)NCHUNK * N_NODES * 4;              // 12.8 MB
    int* perm = (int*)(ws + o); o += (size_t)N_EDGES * 4;                       // 3.2 MB
    int* psrc = (int*)(ws + o); o += (size_t)N_EDGES * 4;                       // 3.2 MB

    hipMemsetAsync(hist, 0, (size_t)NCHUNK * N_NODES * sizeof(int), stream);
    setup_kernel<<<128, 256, 0, stream>>>(W_node, W_edge, WTn, WTe);
    node_kernel<<<(N_NODES + 63) / 64, 256, 0, stream>>>(node_feats, WTn, g_node, b_node, hv);
    hist_kernel<<<NCHUNK, 256, 0, stream>>>(dst, hist);
    tot_kernel<<<(N_NODES + 255) / 256, 256, 0, stream>>>(hist, tot);
    scan1_kernel<<<49, 256, 0, stream>>>(tot, offs, btot);
    scan2_kernel<<<49, 256, 0, stream>>>(offs, btot);
    cursor_kernel<<<(N_NODES + 255) / 256, 256, 0, stream>>>(offs, hist);
    place_kernel<<<NCHUNK, 256, 0, stream>>>(src, dst, hist, perm, psrc);
    agg_kernel<<<N_NODES / 4, 256, 0, stream>>>(edge_feats, perm, psrc, offs, WTe, g_edge, b_edge, hv, h);
    out_kernel<<<(N_NODES + 15) / 16, 256, 0, stream>>>(h, W_out, g_out, b_out, out);
}

// Round 4
// 851.687 us; speedup vs baseline: 3.6173x; 1.6847x over previous
//
#include <hip/hip_runtime.h>

#define N_NODES 50000
#define N_EDGES 800000
#define NODE_IN 256
#define EDGE_IN 64
#define HID 128
#define OUTD 16
#define LN_EPS 1e-5f
#define NCHUNK 128
#define EPC (N_EDGES / NCHUNK)   // 6250 edges per chunk

typedef __attribute__((ext_vector_type(4))) float f32x4;
typedef __attribute__((ext_vector_type(8))) _Float16 half8;
typedef __attribute__((ext_vector_type(4))) _Float16 half4;

__device__ __forceinline__ float gelu_exact(float x) {
    return 0.5f * x * (1.0f + erff(x * 0.70710678118654752f));
}

// ---------------------------------------------------------------------------
// Setup: transpose weights to [col][k] fp16 (MFMA B fragments become 16B loads)
// ---------------------------------------------------------------------------
__global__ void setup_kernel(const float* __restrict__ Wn, const float* __restrict__ We,
                             _Float16* __restrict__ WTn, _Float16* __restrict__ WTe) {
    int t = blockIdx.x * blockDim.x + threadIdx.x;
    int stride = gridDim.x * blockDim.x;
    for (int i = t; i < HID * NODE_IN; i += stride) {
        int n = i >> 8, k = i & 255;
        WTn[i] = (_Float16)Wn[k * HID + n];
    }
    for (int i = t; i < HID * EDGE_IN; i += stride) {
        int n = i >> 6, k = i & 63;
        WTe[i] = (_Float16)We[k * HID + n];
    }
}

// ---------------------------------------------------------------------------
// Deterministic stable counting sort by dst.
// Pass A: per-chunk histograms; 4 blocks cooperate per chunk (atomic int
// counts are order-independent -> deterministic).
// ---------------------------------------------------------------------------
__global__ __launch_bounds__(256) void hist_kernel(const int* __restrict__ dst,
                                                   int* __restrict__ hist) {
    const int k = blockIdx.x >> 2;
    const int part = blockIdx.x & 3;
    int* hk = hist + k * N_NODES;
    const int beg = k * EPC;
    for (int i = part * 256 + threadIdx.x; i < EPC; i += 1024)
        atomicAdd(&hk[dst[beg + i]], 1);
}

// Pass B1: per-node totals across chunks.
__global__ __launch_bounds__(256) void tot_kernel(const int* __restrict__ hist,
                                                  int* __restrict__ tot) {
    int n = blockIdx.x * 256 + threadIdx.x;
    if (n < N_NODES) {
        int s = 0;
        #pragma unroll 8
        for (int k = 0; k < NCHUNK; ++k) s += hist[k * N_NODES + n];
        tot[n] = s;
    }
}

// Scan over tot -> offs (exclusive).  49 blocks x 1024 elements.
__global__ __launch_bounds__(256) void scan1_kernel(const int* __restrict__ tot,
                                                    int* __restrict__ offs,
                                                    int* __restrict__ btot) {
    __shared__ int lsum[256];
    const int t = threadIdx.x;
    const int base = blockIdx.x * 1024 + t * 4;
    int v[4]; int s = 0;
    #pragma unroll
    for (int j = 0; j < 4; ++j) {
        int idx = base + j;
        v[j] = (idx < N_NODES) ? tot[idx] : 0;
        s += v[j];
    }
    lsum[t] = s;
    __syncthreads();
    for (int d = 1; d < 256; d <<= 1) {
        int x = (t >= d) ? lsum[t - d] : 0;
        __syncthreads();
        lsum[t] += x;
        __syncthreads();
    }
    int excl = lsum[t] - s;
    if (t == 255) btot[blockIdx.x] = lsum[255];
    int run = excl;
    #pragma unroll
    for (int j = 0; j < 4; ++j) {
        int idx = base + j;
        if (idx < N_NODES) offs[idx] = run;
        run += v[j];
    }
}

__global__ __launch_bounds__(256) void scan2_kernel(int* __restrict__ offs,
                                                    const int* __restrict__ btot) {
    int s = 0;
    for (int i = 0; i < (int)blockIdx.x; ++i) s += btot[i];
    const int t = threadIdx.x;
    const int base = blockIdx.x * 1024 + t * 4;
    #pragma unroll
    for (int j = 0; j < 4; ++j) {
        int idx = base + j;
        if (idx < N_NODES) offs[idx] += s;
    }
    if (blockIdx.x == 0 && t == 0) offs[N_NODES] = N_EDGES;
}

// Pass B2: convert hist rows to per-chunk starting cursors (in place).
__global__ __launch_bounds__(256) void cursor_kernel(const int* __restrict__ offs,
                                                     int* __restrict__ hist) {
    int n = blockIdx.x * 256 + threadIdx.x;
    if (n < N_NODES) {
        int running = offs[n];
        #pragma unroll 4
        for (int k = 0; k < NCHUNK; ++k) {
            int c = hist[k * N_NODES + n];
            hist[k * N_NODES + n] = running;
            running += c;
        }
    }
}

// Pass C: stable placement.  One block per chunk; 256-edge groups in order.
// Rank within group via LDS-broadcast loop (deterministic); one leader per
// distinct dst per group advances the cursor with one atomic (barrier-ordered
// across groups -> deterministic bases).  Writes psrc[pos], perm[pos] and the
// inverse map spos[e] (coalesced).
__global__ __launch_bounds__(256) void place_kernel(const int* __restrict__ src,
                                                    const int* __restrict__ dst,
                                                    int* __restrict__ cur,
                                                    int* __restrict__ perm,
                                                    int* __restrict__ psrc,
                                                    int* __restrict__ spos) {
    __shared__ int ld[256];
    __shared__ int ls[256];
    __shared__ int lb[256];
    const int k = blockIdx.x;
    const int t = threadIdx.x;
    int* curk = cur + k * N_NODES;
    const int cbeg = k * EPC;
    const int ngroups = (EPC + 255) / 256;
    for (int g = 0; g < ngroups; ++g) {
        const int gbeg = cbeg + g * 256;
        const int count = min(256, cbeg + EPC - gbeg);
        __syncthreads();
        if (t < count) { ld[t] = dst[gbeg + t]; ls[t] = src[gbeg + t]; }
        __syncthreads();
        int rank = 0, leader = -1, total = 0;
        const int d = (t < count) ? ld[t] : -1;
        if (t < count) {
            #pragma unroll 4
            for (int i = 0; i < count; ++i) {
                bool m = (ld[i] == d);
                total += m;
                rank += (m && i < t);
                if (m && leader < 0) leader = i;
            }
            if (rank == 0) {
                int bse = atomicAdd(&curk[d], total);
                lb[t] = bse;
            }
        }
        __syncthreads();
        if (t < count) {
            int pos = lb[leader] + rank;
            perm[pos] = gbeg + t;
            psrc[pos] = ls[t];
            spos[gbeg + t] = pos;
        }
    }
}

// ---------------------------------------------------------------------------
// Node projection: hv = LN(GELU(X @ Wn)), stored fp16 PERMUTED:
// hv[row*128 + x*8 + c] = value at col (16c + x).
// ---------------------------------------------------------------------------
__global__ __launch_bounds__(256) void node_kernel(
    const float* __restrict__ X,
    const _Float16* __restrict__ WT,    // [HID][NODE_IN]
    const float* __restrict__ g, const float* __restrict__ b,
    _Float16* __restrict__ hv)
{
    __shared__ __align__(16) _Float16 lA[64 * 72];
    __shared__ __align__(16) _Float16 lB[128 * 72];

    const int t = threadIdx.x;
    const int wave = t >> 6, lane = t & 63;
    const int x15 = lane & 15, quad = lane >> 4;
    const int row0 = blockIdx.x * 64;

    float gc[8], bc[8];
    #pragma unroll
    for (int c = 0; c < 8; ++c) { gc[c] = g[16 * c + x15]; bc[c] = b[16 * c + x15]; }

    f32x4 acc[8];
    #pragma unroll
    for (int c = 0; c < 8; ++c) acc[c] = (f32x4)(0.0f);

    for (int kc = 0; kc < 4; ++kc) {
        const int k0 = kc * 64;
        __syncthreads();
        #pragma unroll
        for (int j = 0; j < 4; ++j) {
            int idx = j * 1024 + t * 4;
            int r = idx >> 6, kk = idx & 63;
            int grow = row0 + r;
            float4 v = make_float4(0.f, 0.f, 0.f, 0.f);
            if (grow < N_NODES) v = *(const float4*)(X + grow * NODE_IN + k0 + kk);
            half4 h4;
            h4[0] = (_Float16)v.x; h4[1] = (_Float16)v.y;
            h4[2] = (_Float16)v.z; h4[3] = (_Float16)v.w;
            *(half4*)(lA + r * 72 + kk) = h4;
        }
        #pragma unroll
        for (int j = 0; j < 4; ++j) {
            int idx = j * 2048 + t * 8;
            int n = idx >> 6, kk = idx & 63;
            half8 v = *(const half8*)(WT + n * NODE_IN + k0 + kk);
            *(half8*)(lB + n * 72 + kk) = v;
        }
        __syncthreads();
        #pragma unroll
        for (int ks = 0; ks < 2; ++ks) {
            half8 a = *(const half8*)(lA + (wave * 16 + x15) * 72 + ks * 32 + quad * 8);
            #pragma unroll
            for (int c = 0; c < 8; ++c) {
                half8 bb = *(const half8*)(lB + (c * 16 + x15) * 72 + ks * 32 + quad * 8);
                acc[c] = __builtin_amdgcn_mfma_f32_16x16x32_f16(a, bb, acc[c], 0, 0, 0);
            }
        }
    }

    float v[8][4], s[4], sq[4];
    #pragma unroll
    for (int r = 0; r < 4; ++r) { s[r] = 0.f; sq[r] = 0.f; }
    #pragma unroll
    for (int c = 0; c < 8; ++c)
        #pragma unroll
        for (int r = 0; r < 4; ++r) {
            float x = gelu_exact(acc[c][r]);
            v[c][r] = x; s[r] += x; sq[r] += x * x;
        }
    #pragma unroll
    for (int m = 1; m <= 8; m <<= 1)
        #pragma unroll
        for (int r = 0; r < 4; ++r) {
            s[r]  += __shfl_xor(s[r],  m, 64);
            sq[r] += __shfl_xor(sq[r], m, 64);
        }
    #pragma unroll
    for (int r = 0; r < 4; ++r) {
        int row = row0 + wave * 16 + quad * 4 + r;
        if (row >= N_NODES) continue;
        float mean = s[r] * (1.f / 128.f);
        float var  = sq[r] * (1.f / 128.f) - mean * mean;
        float rstd = rsqrtf(var + LN_EPS);
        half8 o;
        #pragma unroll
        for (int c = 0; c < 8; ++c)
            o[c] = (_Float16)((v[c][r] - mean) * rstd * gc[c] + bc[c]);
        *(half8*)(hv + row * HID + x15 * 8) = o;
    }
}

// ---------------------------------------------------------------------------
// Phase E: edge projection in EDGE order (coalesced), he = exp(LN(EF@We))
// stored fp16 at SORTED position spos[e], permuted col layout (matches hv).
// 12500 blocks x 64 edges.  No atomics, deterministic.
// ---------------------------------------------------------------------------
__global__ __launch_bounds__(256) void eproj_kernel(
    const float* __restrict__ EF,
    const int* __restrict__ spos,
    const _Float16* __restrict__ WT,    // [HID][EDGE_IN]
    const float* __restrict__ g, const float* __restrict__ b,
    _Float16* __restrict__ hesort)
{
    __shared__ __align__(16) _Float16 lA[64 * 72];
    __shared__ int lpos[64];

    const int t = threadIdx.x;
    const int wave = t >> 6, lane = t & 63;
    const int x15 = lane & 15, quad = lane >> 4;
    const int e0 = blockIdx.x * 64;

    half8 Bf[8][2];
    #pragma unroll
    for (int c = 0; c < 8; ++c)
        #pragma unroll
        for (int ks = 0; ks < 2; ++ks)
            Bf[c][ks] = *(const half8*)(WT + (c * 16 + x15) * EDGE_IN + ks * 32 + quad * 8);

    float gc[8], bc[8];
    #pragma unroll
    for (int c = 0; c < 8; ++c) { gc[c] = g[16 * c + x15]; bc[c] = b[16 * c + x15]; }

    // stage 64 edges x 64 feats fp32 -> fp16 (wave reads 1KB contiguous)
    #pragma unroll
    for (int j = 0; j < 4; ++j) {
        int idx = j * 1024 + t * 4;
        int r = idx >> 6, kk = idx & 63;
        float4 v = *(const float4*)(EF + (size_t)(e0 + r) * EDGE_IN + kk);
        half4 h4;
        h4[0] = (_Float16)v.x; h4[1] = (_Float16)v.y;
        h4[2] = (_Float16)v.z; h4[3] = (_Float16)v.w;
        *(half4*)(lA + r * 72 + kk) = h4;
    }
    if (t < 64) lpos[t] = spos[e0 + t];
    __syncthreads();

    f32x4 acc[8];
    #pragma unroll
    for (int c = 0; c < 8; ++c) acc[c] = (f32x4)(0.0f);
    #pragma unroll
    for (int ks = 0; ks < 2; ++ks) {
        half8 a = *(const half8*)(lA + (wave * 16 + x15) * 72 + ks * 32 + quad * 8);
        #pragma unroll
        for (int c = 0; c < 8; ++c)
            acc[c] = __builtin_amdgcn_mfma_f32_16x16x32_f16(a, Bf[c][ks], acc[c], 0, 0, 0);
    }

    float s[4], sq[4];
    #pragma unroll
    for (int r = 0; r < 4; ++r) { s[r] = 0.f; sq[r] = 0.f; }
    #pragma unroll
    for (int c = 0; c < 8; ++c)
        #pragma unroll
        for (int r = 0; r < 4; ++r) { float x = acc[c][r]; s[r] += x; sq[r] += x * x; }
    #pragma unroll
    for (int m = 1; m <= 8; m <<= 1)
        #pragma unroll
        for (int r = 0; r < 4; ++r) {
            s[r]  += __shfl_xor(s[r],  m, 64);
            sq[r] += __shfl_xor(sq[r], m, 64);
        }

    #pragma unroll
    for (int r = 0; r < 4; ++r) {
        int erow = wave * 16 + quad * 4 + r;
        int pos = lpos[erow];
        float mean = s[r] * (1.f / 128.f);
        float var  = sq[r] * (1.f / 128.f) - mean * mean;
        float rstd = rsqrtf(var + LN_EPS);
        half8 o;
        #pragma unroll
        for (int c = 0; c < 8; ++c)
            o[c] = (_Float16)__expf((acc[c][r] - mean) * rstd * gc[c] + bc[c]);
        *(half8*)(hesort + (size_t)pos * HID + x15 * 8) = o;
    }
}

// ---------------------------------------------------------------------------
// Phase A: streaming segment-sum.  Wave per node; he rows are consecutive
// (sorted), read 1KB-contiguous per instruction; hv gathered (L2/L3-hot);
// fp32 accumulate; one 512B store per node.  Low VGPR -> high occupancy.
// ---------------------------------------------------------------------------
__global__ __launch_bounds__(256) void agg2_kernel(
    const _Float16* __restrict__ hesort,
    const int* __restrict__ psrc, const int* __restrict__ offs,
    const _Float16* __restrict__ hv,
    float* __restrict__ h)
{
    const int t = threadIdx.x;
    const int wave = t >> 6, lane = t & 63;
    const int x15 = lane & 15, quad = lane >> 4;
    const int n = blockIdx.x * 4 + wave;   // 12500 * 4 = 50000 exact

    const int beg = offs[n], end = offs[n + 1];

    float vacc[8];
    #pragma unroll
    for (int c = 0; c < 8; ++c) vacc[c] = 0.f;

    for (int e0 = beg; e0 < end; e0 += 8) {
        int e1 = e0 + quad, e2 = e0 + 4 + quad;
        bool v1 = e1 < end, v2 = e2 < end;
        int c1 = v1 ? e1 : beg, c2 = v2 ? e2 : beg;
        int s1 = psrc[c1], s2 = psrc[c2];
        half8 a1 = *(const half8*)(hesort + (size_t)c1 * HID + x15 * 8);
        half8 a2 = *(const half8*)(hesort + (size_t)c2 * HID + x15 * 8);
        half8 b1 = *(const half8*)(hv + (size_t)s1 * HID + x15 * 8);
        half8 b2 = *(const half8*)(hv + (size_t)s2 * HID + x15 * 8);
        if (v1) {
            #pragma unroll
            for (int c = 0; c < 8; ++c) vacc[c] += (float)a1[c] * (float)b1[c];
        }
        if (v2) {
            #pragma unroll
            for (int c = 0; c < 8; ++c) vacc[c] += (float)a2[c] * (float)b2[c];
        }
    }

    // reduce across quads -> col sums, write once
    float o8[8];
    #pragma unroll
    for (int c = 0; c < 8; ++c) {
        float v = vacc[c];
        v += __shfl_xor(v, 16, 64);
        v += __shfl_xor(v, 32, 64);
        o8[c] = v;
    }
    if (quad == 0) {
        float* hp = h + (size_t)n * HID + x15 * 8;   // permuted layout p = x15*8 + c
        *(float4*)hp = make_float4(o8[0], o8[1], o8[2], o8[3]);
        *(float4*)(hp + 4) = make_float4(o8[4], o8[5], o8[6], o8[7]);
    }
}

// ---------------------------------------------------------------------------
// Fallback fused aggregation (round-3 path) if d_ws is too small for hesort.
// ---------------------------------------------------------------------------
__global__ __launch_bounds__(256) void agg_kernel(
    const float* __restrict__ EF,
    const int* __restrict__ perm, const int* __restrict__ psrc,
    const int* __restrict__ offs,
    const _Float16* __restrict__ WT,
    const float* __restrict__ g, const float* __restrict__ b,
    const _Float16* __restrict__ hv,
    float* __restrict__ h)
{
    const int t = threadIdx.x;
    const int wave = t >> 6, lane = t & 63;
    const int x15 = lane & 15, quad = lane >> 4;
    const int n = blockIdx.x * 4 + wave;

    half8 Bf[8][2];
    #pragma unroll
    for (int c = 0; c < 8; ++c)
        #pragma unroll
        for (int ks = 0; ks < 2; ++ks)
            Bf[c][ks] = *(const half8*)(WT + (c * 16 + x15) * EDGE_IN + ks * 32 + quad * 8);

    float gc[8], bc[8];
    #pragma unroll
    for (int c = 0; c < 8; ++c) { gc[c] = g[16 * c + x15]; bc[c] = b[16 * c + x15]; }

    const int beg = offs[n], end = offs[n + 1];

    f32x4 vacc[8];
    #pragma unroll
    for (int c = 0; c < 8; ++c) vacc[c] = (f32x4)(0.0f);

    for (int e0 = beg; e0 < end; e0 += 16) {
        int ea = e0 + x15;
        if (ea >= end) ea = end - 1;
        int pe = perm[ea];
        const float* ep = EF + (size_t)pe * EDGE_IN;

        f32x4 acc[8];
        #pragma unroll
        for (int c = 0; c < 8; ++c) acc[c] = (f32x4)(0.0f);

        #pragma unroll
        for (int ks = 0; ks < 2; ++ks) {
            float4 f0 = *(const float4*)(ep + ks * 32 + quad * 8);
            float4 f1 = *(const float4*)(ep + ks * 32 + quad * 8 + 4);
            half8 a;
            a[0] = (_Float16)f0.x; a[1] = (_Float16)f0.y;
            a[2] = (_Float16)f0.z; a[3] = (_Float16)f0.w;
            a[4] = (_Float16)f1.x; a[5] = (_Float16)f1.y;
            a[6] = (_Float16)f1.z; a[7] = (_Float16)f1.w;
            #pragma unroll
            for (int c = 0; c < 8; ++c)
                acc[c] = __builtin_amdgcn_mfma_f32_16x16x32_f16(a, Bf[c][ks], acc[c], 0, 0, 0);
        }

        float s[4], sq[4];
        #pragma unroll
        for (int r = 0; r < 4; ++r) { s[r] = 0.f; sq[r] = 0.f; }
        #pragma unroll
        for (int c = 0; c < 8; ++c)
            #pragma unroll
            for (int r = 0; r < 4; ++r) { float x = acc[c][r]; s[r] += x; sq[r] += x * x; }
        #pragma unroll
        for (int m = 1; m <= 8; m <<= 1)
            #pragma unroll
            for (int r = 0; r < 4; ++r) {
                s[r]  += __shfl_xor(s[r],  m, 64);
                sq[r] += __shfl_xor(sq[r], m, 64);
            }

        #pragma unroll
        for (int r = 0; r < 4; ++r) {
            int er = e0 + quad * 4 + r;
            if (er < end) {
                int se = psrc[er];
                half8 hg = *(const half8*)(hv + (size_t)se * HID + x15 * 8);
                float mean = s[r] * (1.f / 128.f);
                float var  = sq[r] * (1.f / 128.f) - mean * mean;
                float rstd = rsqrtf(var + LN_EPS);
                #pragma unroll
                for (int c = 0; c < 8; ++c) {
                    float he = __expf((acc[c][r] - mean) * rstd * gc[c] + bc[c]);
                    vacc[c][r] += he * (float)hg[c];
                }
            }
        }
    }

    float o8[8];
    #pragma unroll
    for (int c = 0; c < 8; ++c) {
        float v = vacc[c][0] + vacc[c][1] + vacc[c][2] + vacc[c][3];
        v += __shfl_xor(v, 16, 64);
        v += __shfl_xor(v, 32, 64);
        o8[c] = v;
    }
    if (quad == 0) {
        float* hp = h + (size_t)n * HID + x15 * 8;
        *(float4*)hp = make_float4(o8[0], o8[1], o8[2], o8[3]);
        *(float4*)(hp + 4) = make_float4(o8[4], o8[5], o8[6], o8[7]);
    }
}

// ---------------------------------------------------------------------------
// Out projection: out = LN(GELU(h @ Wout)).  Un-permutes h in LDS staging.
// ---------------------------------------------------------------------------
__global__ __launch_bounds__(256) void out_kernel(
    const float* __restrict__ h,
    const float* __restrict__ W,       // [128][16]
    const float* __restrict__ g, const float* __restrict__ b,
    float* __restrict__ out)
{
    __shared__ float lW[HID * OUTD];
    __shared__ float lh[16][HID];
    const int t = threadIdx.x;
    const int node0 = blockIdx.x * 16;

    for (int i = t; i < HID * OUTD; i += 256) lW[i] = W[i];
    for (int i = t; i < 16 * HID; i += 256) {
        int row = i >> 7, p = i & 127;
        int k = 16 * (p & 7) + (p >> 3);     // un-permute: p = x*8 + c -> k = 16c + x
        int grow = node0 + row;
        lh[row][k] = (grow < N_NODES) ? h[grow * HID + p] : 0.f;
    }
    __syncthreads();

    const int i = t >> 4, j = t & 15;
    float acc = 0.f;
    #pragma unroll 8
    for (int k = 0; k < HID; ++k)
        acc = fmaf(lh[i][k], lW[k * OUTD + j], acc);
    float x = gelu_exact(acc);
    float s = x, sq = x * x;
    #pragma unroll
    for (int m = 1; m <= 8; m <<= 1) {
        s  += __shfl_xor(s,  m, 64);
        sq += __shfl_xor(sq, m, 64);
    }
    float mean = s * (1.f / 16.f);
    float var  = sq * (1.f / 16.f) - mean * mean;
    float rstd = rsqrtf(var + LN_EPS);
    int grow = node0 + i;
    if (grow < N_NODES) out[grow * OUTD + j] = (x - mean) * rstd * g[j] + b[j];
}

// ---------------------------------------------------------------------------
extern "C" void kernel_launch(void* const* d_in, const int* in_sizes, int n_in,
                              void* d_out, int out_size, void* d_ws, size_t ws_size,
                              hipStream_t stream) {
    const float* node_feats = (const float*)d_in[0];
    const float* edge_feats = (const float*)d_in[1];
    const int*   src        = (const int*)d_in[2];
    const int*   dst        = (const int*)d_in[3];
    const float* W_node     = (const float*)d_in[4];
    const float* g_node     = (const float*)d_in[5];
    const float* b_node     = (const float*)d_in[6];
    const float* W_edge     = (const float*)d_in[7];
    const float* g_edge     = (const float*)d_in[8];
    const float* b_edge     = (const float*)d_in[9];
    const float* W_out      = (const float*)d_in[10];
    const float* g_out      = (const float*)d_in[11];
    const float* b_out      = (const float*)d_in[12];
    float* out = (float*)d_out;

    char* ws = (char*)d_ws;
    size_t o = 0;
    _Float16* hv  = (_Float16*)(ws + o); o += (size_t)N_NODES * HID * 2;        // 12.8 MB
    float*    h   = (float*)(ws + o);    o += (size_t)N_NODES * HID * 4;        // 25.6 MB
    _Float16* WTn = (_Float16*)(ws + o); o += (size_t)HID * NODE_IN * 2;        // 64 KB
    _Float16* WTe = (_Float16*)(ws + o); o += (size_t)HID * EDGE_IN * 2;        // 16 KB
    int* tot  = (int*)(ws + o); o += (size_t)N_NODES * 4;                       // 200 KB
    int* offs = (int*)(ws + o); o += (size_t)(N_NODES + 16) * 4;                // 200 KB
    int* btot = (int*)(ws + o); o += 1024;
    int* hist = (int*)(ws + o); o += (size_t)NCHUNK * N_NODES * 4;              // 25.6 MB
    int* perm = (int*)(ws + o); o += (size_t)N_EDGES * 4;                       // 3.2 MB
    int* psrc = (int*)(ws + o); o += (size_t)N_EDGES * 4;                       // 3.2 MB
    int* spos = (int*)(ws + o); o += (size_t)N_EDGES * 4;                       // 3.2 MB
    _Float16* hesort = (_Float16*)(ws + o);
    size_t need = o + (size_t)N_EDGES * HID * 2;                                // +204.8 MB
    const bool two_phase = (ws_size >= need);   // constant across calls: capture-safe

    hipMemsetAsync(hist, 0, (size_t)NCHUNK * N_NODES * sizeof(int), stream);
    setup_kernel<<<128, 256, 0, stream>>>(W_node, W_edge, WTn, WTe);
    node_kernel<<<(N_NODES + 63) / 64, 256, 0, stream>>>(node_feats, WTn, g_node, b_node, hv);
    hist_kernel<<<NCHUNK * 4, 256, 0, stream>>>(dst, hist);
    tot_kernel<<<(N_NODES + 255) / 256, 256, 0, stream>>>(hist, tot);
    scan1_kernel<<<49, 256, 0, stream>>>(tot, offs, btot);
    scan2_kernel<<<49, 256, 0, stream>>>(offs, btot);
    cursor_kernel<<<(N_NODES + 255) / 256, 256, 0, stream>>>(offs, hist);
    place_kernel<<<NCHUNK, 256, 0, stream>>>(src, dst, hist, perm, psrc, spos);
    if (two_phase) {
        eproj_kernel<<<N_EDGES / 64, 256, 0, stream>>>(edge_feats, spos, WTe, g_edge, b_edge, hesort);
        agg2_kernel<<<N_NODES / 4, 256, 0, stream>>>(hesort, psrc, offs, hv, h);
    } else {
        agg_kernel<<<N_NODES / 4, 256, 0, stream>>>(edge_feats, perm, psrc, offs, WTe, g_edge, b_edge, hv, h);
    }
    out_kernel<<<(N_NODES + 15) / 16, 256, 0, stream>>>(h, W_out, g_out, b_out, out);
}